// Round 15
// baseline (244.677 us; speedup 1.0000x reference)
//
#include <hip/hip_runtime.h>
#include <stdint.h>

#define NB 4096
#define NT 200
#define NE 64
// attention: 4E=256 -> 64 -> 32 -> 1 ; final MLP: 272 -> 256 -> 128 -> 1
//
// ABI (proven R2-R10): identity order, fp32 floats, int32 ints, FP32 output.
//
// R28: pre-transposed bf16 weight tables for din_mlp.
//  - R27 post-mortem: MFMA mlp only 133->108us. The cost was never the
//    math: each B-fragment = 8 dependent scalar dword loads (strided
//    w1[k*256+n]) + cvt8a, ~208 scalar loads/wave on the critical path
//    at 1 block/CU. MFMA itself trivial.
//  - Now: din_prep (416 blocks, ~3us) converts W1/W2 ONCE into
//    __device__ bf16 hi/lo tables in fragment-ready [n][k] layout
//    (k-contiguous, zero-padded k in [272,288)). B-fragment = ONE b128
//    vector load; cvt gone; pad branch gone. X staging vectorized
//    (float4 reads, bf16x4 LDS stores). Tables 426KB -> L2-resident.
//  - din_attn: UNchanged from R26/R27 (isolate the mlp change).

typedef __attribute__((ext_vector_type(8))) __bf16 bf16x8;
typedef __attribute__((ext_vector_type(4))) __bf16 bf16x4;
typedef __attribute__((ext_vector_type(4))) float f32x4;

__device__ __bf16 g_w1h[256 * 288];   // [n][k], k-pad [272,288) = 0
__device__ __bf16 g_w1l[256 * 288];
__device__ __bf16 g_w2h[128 * 256];   // [n][k]
__device__ __bf16 g_w2l[128 * 256];

__device__ __forceinline__ void cvt8(const float4 a, const float4 b,
                                     bf16x8& hi, bf16x8& lo)
{
    float x[8] = {a.x, a.y, a.z, a.w, b.x, b.y, b.z, b.w};
#pragma unroll
    for (int i = 0; i < 8; ++i) {
        const __bf16 h = (__bf16)x[i];
        hi[i] = h;
        lo[i] = (__bf16)(x[i] - (float)h);
    }
}

// ---------------------------------------------------------------------------
// Prep: W1 [k][n] -> g_w1{h,l} [n][288]; W2 [k][n2] -> g_w2{h,l} [n2][256]
// ---------------------------------------------------------------------------
__global__ void din_prep(const float* __restrict__ w1,
                         const float* __restrict__ w2)
{
    const int i = blockIdx.x * 256 + threadIdx.x;
    if (i < 256 * 288) {
        const int n = i / 288, k = i - n * 288;
        const float v = (k < 272) ? w1[(size_t)k * 256 + n] : 0.f;
        const __bf16 h = (__bf16)v;
        g_w1h[i] = h;
        g_w1l[i] = (__bf16)(v - (float)h);
    } else {
        const int j = i - 256 * 288;
        if (j < 128 * 256) {
            const int n = j / 256, k = j - n * 256;
            const float v = w2[(size_t)k * 128 + n];
            const __bf16 h = (__bf16)v;
            g_w2h[j] = h;
            g_w2l[j] = (__bf16)(v - (float)h);
        }
    }
}

struct __align__(16) SmemM {
    __bf16 wT_hi[64 * 72];    // WeffT[j][k], pitch 72 (144B, b128-aligned)
    __bf16 wT_lo[64 * 72];
    __bf16 w2T_hi[32 * 72];   // w2T[o][j]
    __bf16 w2T_lo[32 * 72];
    float  q[64];
    float  biasj[64];
    float  b2[32];
    float  wo[32];
    float  ip[8 * 64];        // bias partials, later interest partials
    float  red_a[8];
    float  red_b[8];
    float  scores[256];
    float  bounce[8][16 * 36];  // per-wave transpose buffer (pitch 36 dw)
};                               // ~50.0 KB -> 3 blocks/CU

__global__ __launch_bounds__(512)
void din_attn(const int* __restrict__ target_item,
              const int* __restrict__ history_items,
              const int* __restrict__ history_mask,
              const int* __restrict__ sparse_features,
              const float* __restrict__ dense_features,
              const float* __restrict__ item_table,
              const float* __restrict__ user_table,
              const float* __restrict__ ctx_table,
              const float* __restrict__ att_w1,
              const float* __restrict__ att_b1,
              const float* __restrict__ att_w2,
              const float* __restrict__ att_b2,
              const float* __restrict__ att_wo,
              const float* __restrict__ att_bo,
              float* __restrict__ mlp_in)   // [NB][272]
{
    __shared__ SmemM sm;

    const int b    = blockIdx.x;
    const int tid  = threadIdx.x;    // 0..511
    const int wv   = tid >> 6;       // wave 0..7
    const int lane = tid & 63;
    const int l15  = lane & 15;
    const int g4   = lane >> 4;      // 0..3

    // ---- A-fragments: wave owns rows 32*wv + mt*16 + l15, mt=0..1 -------
    bf16x8 khi[2][2], klo[2][2];
#pragma unroll
    for (int mt = 0; mt < 2; ++mt) {
        int t = 32 * wv + mt * 16 + l15;
        if (t > NT - 1) t = NT - 1;                 // dead rows: masked later
        const int hr = history_items[(size_t)b * NT + t];
        const float* kp = item_table + (size_t)hr * NE + g4 * 8;
#pragma unroll
        for (int ks = 0; ks < 2; ++ks) {
            const float4 f0 = *(const float4*)(kp + ks * 32);
            const float4 f1 = *(const float4*)(kp + ks * 32 + 4);
            cvt8(f0, f1, khi[mt][ks], klo[mt][ks]);
        }
    }

    // ---- epilogue prefetch (independent loads; 3 VGPRs) -----------------
    float pre_u = 0.f, pre_c = 0.f, pre_d = 0.f;
    if (tid < NE) {
        pre_u = user_table[(size_t)sparse_features[b * 2 + 0] * NE + tid];
        pre_c = ctx_table[(size_t)sparse_features[b * 2 + 1] * NE + tid];
    } else if (tid < 80) {
        pre_d = dense_features[(size_t)b * 16 + (tid - 64)];
    }

    // ---- stage q, b2, wo -------------------------------------------------
    if (tid < NE) sm.q[tid] = item_table[(size_t)target_item[b] * NE + tid];
    if (tid < 32) { sm.b2[tid] = att_b2[tid]; sm.wo[tid] = att_wo[tid]; }
    const float bo = att_bo[0];
    __syncthreads();

    // ---- Weff^T split staging (1 b128 store/thread) + bias partials -----
    {
        const int j  = tid & 63;
        const int eb = (tid >> 6) * 8;   // 8 consecutive e per thread
        float pb = 0.f;
        bf16x8 vhi, vlo;
#pragma unroll
        for (int i = 0; i < 8; ++i) {
            const int e = eb + i;
            const float qe = sm.q[e];
            const float A  = att_w1[(size_t)(e)       * NE + j];
            const float Bv = att_w1[(size_t)(64 + e)  * NE + j];
            const float C  = att_w1[(size_t)(128 + e) * NE + j];
            const float D  = att_w1[(size_t)(192 + e) * NE + j];
            const float wf = A + C + qe * D;
            const __bf16 h = (__bf16)wf;
            vhi[i] = h;
            vlo[i] = (__bf16)(wf - (float)h);
            pb += qe * (Bv - C);
        }
        *(bf16x8*)(sm.wT_hi + (size_t)j * 72 + eb) = vhi;
        *(bf16x8*)(sm.wT_lo + (size_t)j * 72 + eb) = vlo;
        sm.ip[(tid >> 6) * 64 + j] = pb;
    }
    // w2T[o][j] split staging (b64 stores, 4 j per thread)
    {
        const int o  = tid & 31;
        const int jb = (tid >> 5) * 4;   // 0..60
        bf16x4 vhi, vlo;
#pragma unroll
        for (int i = 0; i < 4; ++i) {
            const float v = att_w2[(size_t)(jb + i) * 32 + o];
            const __bf16 h = (__bf16)v;
            vhi[i] = h;
            vlo[i] = (__bf16)(v - (float)h);
        }
        *(bf16x4*)(sm.w2T_hi + (size_t)o * 72 + jb) = vhi;
        *(bf16x4*)(sm.w2T_lo + (size_t)o * 72 + jb) = vlo;
    }
    __syncthreads();
    if (tid < NE) {
        float s = att_b1[tid];
#pragma unroll
        for (int w = 0; w < 8; ++w) s += sm.ip[w * 64 + tid];
        sm.biasj[tid] = s;
    }
    __syncthreads();

    // ---- L1 GEMM: h1 = K . Weff  (split-3, 48 MFMA/wave) ----------------
    f32x4 acc1[2][4];
    {
        const f32x4 z = {0.f, 0.f, 0.f, 0.f};
#pragma unroll
        for (int mt = 0; mt < 2; ++mt)
#pragma unroll
            for (int nt = 0; nt < 4; ++nt) acc1[mt][nt] = z;
    }
#pragma unroll
    for (int nt = 0; nt < 4; ++nt) {
        const __bf16* bph = sm.wT_hi + (nt * 16 + l15) * 72 + g4 * 8;
        const __bf16* bpl = sm.wT_lo + (nt * 16 + l15) * 72 + g4 * 8;
        const bf16x8 bh0 = *(const bf16x8*)(bph);
        const bf16x8 bh1 = *(const bf16x8*)(bph + 32);
        const bf16x8 bl0 = *(const bf16x8*)(bpl);
        const bf16x8 bl1 = *(const bf16x8*)(bpl + 32);
#pragma unroll
        for (int mt = 0; mt < 2; ++mt) {
            f32x4 a = acc1[mt][nt];
            a = __builtin_amdgcn_mfma_f32_16x16x32_bf16(khi[mt][0], bh0, a, 0, 0, 0);
            a = __builtin_amdgcn_mfma_f32_16x16x32_bf16(khi[mt][0], bl0, a, 0, 0, 0);
            a = __builtin_amdgcn_mfma_f32_16x16x32_bf16(klo[mt][0], bh0, a, 0, 0, 0);
            a = __builtin_amdgcn_mfma_f32_16x16x32_bf16(khi[mt][1], bh1, a, 0, 0, 0);
            a = __builtin_amdgcn_mfma_f32_16x16x32_bf16(khi[mt][1], bl1, a, 0, 0, 0);
            a = __builtin_amdgcn_mfma_f32_16x16x32_bf16(klo[mt][1], bh1, a, 0, 0, 0);
            acc1[mt][nt] = a;
        }
    }

    // ---- bias + ReLU on C1 (col = nt*16+l15, row-in-tile = g4*4+r) ------
#pragma unroll
    for (int nt = 0; nt < 4; ++nt) {
        const float bj = sm.biasj[nt * 16 + l15];
#pragma unroll
        for (int mt = 0; mt < 2; ++mt)
#pragma unroll
            for (int r = 0; r < 4; ++r)
                acc1[mt][nt][r] = fmaxf(acc1[mt][nt][r] + bj, 0.f);
    }

    // ---- transpose C1-layout -> A2-fragments via wave-private bounce ----
    bf16x8 a2hi[2][2], a2lo[2][2];
    {
        float* bnc = sm.bounce[wv];
#pragma unroll
        for (int mt = 0; mt < 2; ++mt) {
#pragma unroll
            for (int k2s = 0; k2s < 2; ++k2s) {
#pragma unroll
                for (int ntl = 0; ntl < 2; ++ntl) {
                    const int nt = k2s * 2 + ntl;
#pragma unroll
                    for (int r = 0; r < 4; ++r)
                        bnc[(g4 * 4 + r) * 36 + ntl * 16 + l15] = acc1[mt][nt][r];
                }
                // same-wave DS ops are ordered; compiler inserts lgkm waits
                const float* rp = bnc + l15 * 36 + g4 * 8;
                const float4 u0 = *(const float4*)(rp);
                const float4 u1 = *(const float4*)(rp + 4);
                cvt8(u0, u1, a2hi[mt][k2s], a2lo[mt][k2s]);
            }
        }
    }

    // ---- L2 GEMM: h2 = h1 . W2 (split-3, 24 MFMA/wave) ------------------
    f32x4 acc2[2][2];
    {
        const f32x4 z = {0.f, 0.f, 0.f, 0.f};
#pragma unroll
        for (int mt = 0; mt < 2; ++mt) { acc2[mt][0] = z; acc2[mt][1] = z; }
    }
#pragma unroll
    for (int nt2 = 0; nt2 < 2; ++nt2) {
        const __bf16* bph = sm.w2T_hi + (nt2 * 16 + l15) * 72 + g4 * 8;
        const __bf16* bpl = sm.w2T_lo + (nt2 * 16 + l15) * 72 + g4 * 8;
        const bf16x8 bh0 = *(const bf16x8*)(bph);
        const bf16x8 bh1 = *(const bf16x8*)(bph + 32);
        const bf16x8 bl0 = *(const bf16x8*)(bpl);
        const bf16x8 bl1 = *(const bf16x8*)(bpl + 32);
#pragma unroll
        for (int mt = 0; mt < 2; ++mt) {
            f32x4 a = acc2[mt][nt2];
            a = __builtin_amdgcn_mfma_f32_16x16x32_bf16(a2hi[mt][0], bh0, a, 0, 0, 0);
            a = __builtin_amdgcn_mfma_f32_16x16x32_bf16(a2hi[mt][0], bl0, a, 0, 0, 0);
            a = __builtin_amdgcn_mfma_f32_16x16x32_bf16(a2lo[mt][0], bh0, a, 0, 0, 0);
            a = __builtin_amdgcn_mfma_f32_16x16x32_bf16(a2hi[mt][1], bh1, a, 0, 0, 0);
            a = __builtin_amdgcn_mfma_f32_16x16x32_bf16(a2hi[mt][1], bl1, a, 0, 0, 0);
            a = __builtin_amdgcn_mfma_f32_16x16x32_bf16(a2lo[mt][1], bh1, a, 0, 0, 0);
            acc2[mt][nt2] = a;
        }
    }

    // ---- L3 scores: relu(h2+b2).wo, reduce over the 16 col-lanes --------
    float sc[2][4];
#pragma unroll
    for (int mt = 0; mt < 2; ++mt)
#pragma unroll
        for (int r = 0; r < 4; ++r) sc[mt][r] = 0.f;
#pragma unroll
    for (int nt2 = 0; nt2 < 2; ++nt2) {
        const float bb = sm.b2[nt2 * 16 + l15];
        const float ww = sm.wo[nt2 * 16 + l15];
#pragma unroll
        for (int mt = 0; mt < 2; ++mt)
#pragma unroll
            for (int r = 0; r < 4; ++r)
                sc[mt][r] += fmaxf(acc2[mt][nt2][r] + bb, 0.f) * ww;
    }
#pragma unroll
    for (int mt = 0; mt < 2; ++mt)
#pragma unroll
        for (int r = 0; r < 4; ++r) {
            float v = sc[mt][r];
            v += __shfl_xor(v, 1);
            v += __shfl_xor(v, 2);
            v += __shfl_xor(v, 4);
            v += __shfl_xor(v, 8);
            sc[mt][r] = v;
        }
    if (l15 == 0) {
#pragma unroll
        for (int mt = 0; mt < 2; ++mt)
#pragma unroll
            for (int r = 0; r < 4; ++r) {
                const int t = 32 * wv + mt * 16 + g4 * 4 + r;
                float val;
                if (t < NT) {
                    const int mk = history_mask[(size_t)b * NT + t];
                    val = (mk != 0) ? (sc[mt][r] + bo) : -1e9f;
                } else {
                    val = -INFINITY;       // pad rows excluded from softmax
                }
                sm.scores[t] = val;
            }
    }
    __syncthreads();

    // ---- softmax over 256 slots (8-wave reduce; tid>=256 inert) ---------
    const float v = (tid < 256) ? sm.scores[tid] : -INFINITY;
    float m = v;
#pragma unroll
    for (int s = 32; s; s >>= 1) m = fmaxf(m, __shfl_xor(m, s));
    if (lane == 0) sm.red_a[wv] = m;
    __syncthreads();
    float mx = sm.red_a[0];
#pragma unroll
    for (int w = 1; w < 8; ++w) mx = fmaxf(mx, sm.red_a[w]);
    const float ex = __expf(v - mx);   // -inf -> 0
    float ssum = ex;
#pragma unroll
    for (int s = 32; s; s >>= 1) ssum += __shfl_xor(ssum, s);
    if (lane == 0) sm.red_b[wv] = ssum;
    __syncthreads();
    float total = 0.f;
#pragma unroll
    for (int w = 0; w < 8; ++w) total += sm.red_b[w];
    if (tid < 256) sm.scores[tid] = ex / total;   // softmax weight of slot
    __syncthreads();

    // ---- interest in FP32: re-gather K rows (L2/L3-hot), 25 t per wave --
    {
        const int e = lane;            // 0..63
        float acc = 0.f;
        const int tb = 25 * wv;        // 8 waves x 25 = 200 exactly
#pragma unroll 5
        for (int i = 0; i < 25; ++i) {
            const int t = tb + i;
            const float wt = sm.scores[t];
            const int hr = history_items[(size_t)b * NT + t];
            acc += wt * item_table[(size_t)hr * NE + e];
        }
        sm.ip[wv * 64 + e] = acc;
    }
    __syncthreads();

    // ---- assemble mlp_in row [user, ctx, q, interest, dense] ------------
    float* row = mlp_in + (size_t)b * 272;
    if (tid < NE) {
        float inter = 0.f;
#pragma unroll
        for (int w = 0; w < 8; ++w) inter += sm.ip[w * 64 + tid];
        row[0 + tid]   = pre_u;
        row[64 + tid]  = pre_c;
        row[128 + tid] = sm.q[tid];
        row[192 + tid] = inter;
    } else if (tid >= 64 && tid < 80) {
        row[256 + (tid - 64)] = pre_d;
    }
}

// ---------------------------------------------------------------------------
// Kernel 2: final MLP 272 -> 256 -> 128 -> 1 via MFMA (split-3 bf16),
// B-fragments from pre-transposed bf16 tables (1 b128 load each).
// Block = 16 batch rows, 512 threads (8 waves), grid 256.
// ---------------------------------------------------------------------------
#define XP 296   // LDS K-pitch: 148 dw = 20 mod 32 -> 2-way banks (free)

struct __align__(16) SmemL {
    __bf16 xh[16 * XP];    // X rows, bf16-hi, zero-padded k in [272,296)
    __bf16 xl[16 * XP];
    __bf16 h1h[16 * XP];   // h1 rows (k = n1 in [0,256))
    __bf16 h1l[16 * XP];
    float  b1v[256];
    float  b2v[128];
    float  owv[128];
    float  part[8][16];
};                          // ~40.4 KB

__global__ __launch_bounds__(512)
void din_mlp(const float* __restrict__ mlp_in,
             const float* __restrict__ b1,
             const float* __restrict__ b2,
             const float* __restrict__ ow,
             const float* __restrict__ ob,
             float* __restrict__ out)
{
    __shared__ SmemL sm;

    const int b0   = blockIdx.x * 16;
    const int tid  = threadIdx.x;    // 0..511
    const int wv   = tid >> 6;       // wave 0..7
    const int lane = tid & 63;
    const int l15  = lane & 15;
    const int g4   = lane >> 4;      // 0..3

    // ---- stage X rows as bf16 hi/lo (vectorized), zero-pad [272,296) ----
    for (int i = tid; i < 16 * 6; i += 512) {       // 16 rows x 6 bf16x4 pads
        const int r = i / 6, c = i - r * 6;
        const bf16x4 z = {(__bf16)0.f, (__bf16)0.f, (__bf16)0.f, (__bf16)0.f};
        *(bf16x4*)(sm.xh + r * XP + 272 + c * 4) = z;
        *(bf16x4*)(sm.xl + r * XP + 272 + c * 4) = z;
    }
    for (int i = tid; i < 16 * 68; i += 512) {      // 16 rows x 68 float4
        const int r = i / 68, c = i - r * 68;
        const float4 v = *((const float4*)(mlp_in + (size_t)(b0 + r) * 272) + c);
        float x[4] = {v.x, v.y, v.z, v.w};
        bf16x4 h, l;
#pragma unroll
        for (int q = 0; q < 4; ++q) {
            const __bf16 hh = (__bf16)x[q];
            h[q] = hh;
            l[q] = (__bf16)(x[q] - (float)hh);
        }
        *(bf16x4*)(sm.xh + r * XP + c * 4) = h;
        *(bf16x4*)(sm.xl + r * XP + c * 4) = l;
    }
    if (tid < 256) sm.b1v[tid] = b1[tid];
    else if (tid < 384) sm.b2v[tid - 256] = b2[tid - 256];
    else sm.owv[tid - 384] = ow[tid - 384];
    __syncthreads();

    // ---- GEMM1: h1[16x256] = X[16x288] . W1  (54 MFMA/wave) -------------
    f32x4 acc[2];
    {
        const f32x4 z = {0.f, 0.f, 0.f, 0.f};
        acc[0] = z; acc[1] = z;
    }
    const int n0 = wv * 32 + l15;        // nt=0 col
    const int n1 = wv * 32 + 16 + l15;   // nt=1 col
#pragma unroll
    for (int ks = 0; ks < 9; ++ks) {
        const bf16x8 ah = *(const bf16x8*)(sm.xh + l15 * XP + ks * 32 + g4 * 8);
        const bf16x8 al = *(const bf16x8*)(sm.xl + l15 * XP + ks * 32 + g4 * 8);
        const int ko = ks * 32 + g4 * 8;
        const bf16x8 bh0 = *(const bf16x8*)(g_w1h + (size_t)n0 * 288 + ko);
        const bf16x8 bl0 = *(const bf16x8*)(g_w1l + (size_t)n0 * 288 + ko);
        const bf16x8 bh1 = *(const bf16x8*)(g_w1h + (size_t)n1 * 288 + ko);
        const bf16x8 bl1 = *(const bf16x8*)(g_w1l + (size_t)n1 * 288 + ko);
        acc[0] = __builtin_amdgcn_mfma_f32_16x16x32_bf16(ah, bh0, acc[0], 0, 0, 0);
        acc[0] = __builtin_amdgcn_mfma_f32_16x16x32_bf16(ah, bl0, acc[0], 0, 0, 0);
        acc[0] = __builtin_amdgcn_mfma_f32_16x16x32_bf16(al, bh0, acc[0], 0, 0, 0);
        acc[1] = __builtin_amdgcn_mfma_f32_16x16x32_bf16(ah, bh1, acc[1], 0, 0, 0);
        acc[1] = __builtin_amdgcn_mfma_f32_16x16x32_bf16(ah, bl1, acc[1], 0, 0, 0);
        acc[1] = __builtin_amdgcn_mfma_f32_16x16x32_bf16(al, bh1, acc[1], 0, 0, 0);
    }

    // ---- bias + relu, split, write h1 to LDS ----------------------------
#pragma unroll
    for (int nt = 0; nt < 2; ++nt) {
        const int n = wv * 32 + nt * 16 + l15;
        const float bias = sm.b1v[n];
#pragma unroll
        for (int r = 0; r < 4; ++r) {
            const float v = fmaxf(acc[nt][r] + bias, 0.f);
            const __bf16 h = (__bf16)v;
            sm.h1h[(g4 * 4 + r) * XP + n] = h;
            sm.h1l[(g4 * 4 + r) * XP + n] = (__bf16)(v - (float)h);
        }
    }
    __syncthreads();

    // ---- GEMM2: h2[16x128] = h1[16x256] . W2  (24 MFMA/wave) ------------
    f32x4 acc2;
    {
        const f32x4 z = {0.f, 0.f, 0.f, 0.f};
        acc2 = z;
    }
    const int n2 = wv * 16 + l15;
#pragma unroll
    for (int ks = 0; ks < 8; ++ks) {
        const bf16x8 ah = *(const bf16x8*)(sm.h1h + l15 * XP + ks * 32 + g4 * 8);
        const bf16x8 al = *(const bf16x8*)(sm.h1l + l15 * XP + ks * 32 + g4 * 8);
        const int ko = ks * 32 + g4 * 8;
        const bf16x8 bh = *(const bf16x8*)(g_w2h + (size_t)n2 * 256 + ko);
        const bf16x8 bl = *(const bf16x8*)(g_w2l + (size_t)n2 * 256 + ko);
        acc2 = __builtin_amdgcn_mfma_f32_16x16x32_bf16(ah, bh, acc2, 0, 0, 0);
        acc2 = __builtin_amdgcn_mfma_f32_16x16x32_bf16(ah, bl, acc2, 0, 0, 0);
        acc2 = __builtin_amdgcn_mfma_f32_16x16x32_bf16(al, bh, acc2, 0, 0, 0);
    }

    // ---- GEMM3: out = relu(h2+b2) . ow + ob -----------------------------
    {
        const float bias = sm.b2v[n2];
        const float ww   = sm.owv[n2];
        float s[4];
#pragma unroll
        for (int r = 0; r < 4; ++r) {
            float v = fmaxf(acc2[r] + bias, 0.f) * ww;
            v += __shfl_xor(v, 1);
            v += __shfl_xor(v, 2);
            v += __shfl_xor(v, 4);
            v += __shfl_xor(v, 8);
            s[r] = v;
        }
        if (l15 == 0) {
#pragma unroll
            for (int r = 0; r < 4; ++r)
                sm.part[wv][g4 * 4 + r] = s[r];
        }
    }
    __syncthreads();
    if (tid < 16) {
        float o = ob[0];
#pragma unroll
        for (int w = 0; w < 8; ++w) o += sm.part[w][tid];
        out[b0 + tid] = o;
    }
}

// ---------------------------------------------------------------------------
extern "C" void kernel_launch(void* const* d_in, const int* in_sizes, int n_in,
                              void* d_out, int out_size, void* d_ws, size_t ws_size,
                              hipStream_t stream)
{
    float* mlp_in = (float*)d_ws;   // 4096*272*4 = 4.46 MB

    din_prep<<<416, 256, 0, stream>>>(
        (const float*)d_in[14], (const float*)d_in[16]);  // mlp_w1, mlp_w2

    din_attn<<<NB, 512, 0, stream>>>(
        (const int*)d_in[0],      // target_item
        (const int*)d_in[1],      // history_items
        (const int*)d_in[2],      // history_mask
        (const int*)d_in[3],      // sparse_features
        (const float*)d_in[4],    // dense_features
        (const float*)d_in[5],    // item_table
        (const float*)d_in[6],    // user_table
        (const float*)d_in[7],    // ctx_table
        (const float*)d_in[8],  (const float*)d_in[9],   // att_w1, att_b1
        (const float*)d_in[10], (const float*)d_in[11],  // att_w2, att_b2
        (const float*)d_in[12], (const float*)d_in[13],  // att_wo, att_bo
        mlp_in);

    din_mlp<<<NB / 16, 512, 0, stream>>>(
        mlp_in,
        (const float*)d_in[15],   // mlp_b1
        (const float*)d_in[17],   // mlp_b2
        (const float*)d_in[18], (const float*)d_in[19],  // out_w, out_b
        (float*)d_out);
}